// Round 1
// baseline (139.097 us; speedup 1.0000x reference)
//
#include <hip/hip_runtime.h>
#include <stdint.h>

// DVH global loss, MI355X.
// B=4 batches, N=2^21 voxels/batch, 500 bins over [0,75].
// loss = mean_{b,j} ( suffix_sum_{k>j}(hist_p[b]-hist_g[b])[k] / (maskcount_b+1e-6) )^2

#define NBINS 500
#define NHIST 501          // searchsorted index c in [0,500]; c>=1 for d>=0
#define BATCH 4
#define NPB (1 << 21)      // elements per batch
#define VPB (NPB / 4)      // float4 per batch
#define THREADS 256
#define BLOCKS_PER_BATCH 128

// workspace layout (uint32):
//   hist_pred : [b*512 + i], i<501, b<4      (offset 0)
//   hist_gt   : [2048 + b*512 + i]
//   maskcount : [4096 + b]
#define HG_OFF 2048
#define MC_OFF 4096
#define WS_UINTS 4100

__device__ __forceinline__ int bin_of(float d) {
    // c = # of fp32 bins k*STEP that are <= d  (jnp.linspace(0,75,500) semantics,
    // searchsorted side='right'); d >= 0 guaranteed.
    const float STEP = 75.0f / 499.0f;
    const float INV  = 499.0f / 75.0f;
    int k = (int)(d * INV);
    if (k > 499) k = 499;
    if ((float)k * STEP > d) --k;
    else if (k < 499 && (float)(k + 1) * STEP <= d) ++k;
    if ((float)k * STEP > d) --k;   // safety second pass (k>=0 since bins[0]=0<=d)
    return k + 1;                   // in [1,500]
}

__global__ __launch_bounds__(THREADS) void dvh_hist_kernel(
        const float4* __restrict__ dp, const float4* __restrict__ dg,
        const float4* __restrict__ dm, unsigned int* __restrict__ ws) {
    __shared__ unsigned int shp[NHIST];
    __shared__ unsigned int shg[NHIST];
    __shared__ unsigned int smc;
    const int b = blockIdx.y;
    for (int i = threadIdx.x; i < NHIST; i += THREADS) { shp[i] = 0u; shg[i] = 0u; }
    if (threadIdx.x == 0) smc = 0u;
    __syncthreads();

    const size_t base = (size_t)b * VPB;
    unsigned int myc = 0;
    for (int i = blockIdx.x * THREADS + threadIdx.x; i < VPB;
         i += BLOCKS_PER_BATCH * THREADS) {
        float4 p = dp[base + i];
        float4 g = dg[base + i];
        float4 m = dm[base + i];
        if (m.x != 0.0f) { atomicAdd(&shp[bin_of(p.x)], 1u); atomicAdd(&shg[bin_of(g.x)], 1u); ++myc; }
        if (m.y != 0.0f) { atomicAdd(&shp[bin_of(p.y)], 1u); atomicAdd(&shg[bin_of(g.y)], 1u); ++myc; }
        if (m.z != 0.0f) { atomicAdd(&shp[bin_of(p.z)], 1u); atomicAdd(&shg[bin_of(g.z)], 1u); ++myc; }
        if (m.w != 0.0f) { atomicAdd(&shp[bin_of(p.w)], 1u); atomicAdd(&shg[bin_of(g.w)], 1u); ++myc; }
    }
    if (myc) atomicAdd(&smc, myc);
    __syncthreads();

    for (int i = threadIdx.x; i < NHIST; i += THREADS) {
        unsigned int vp = shp[i]; if (vp) atomicAdd(&ws[b * 512 + i], vp);
        unsigned int vg = shg[i]; if (vg) atomicAdd(&ws[HG_OFF + b * 512 + i], vg);
    }
    if (threadIdx.x == 0 && smc) atomicAdd(&ws[MC_OFF + b], smc);
}

__global__ __launch_bounds__(512) void dvh_reduce_kernel(
        const unsigned int* __restrict__ ws, float* __restrict__ out) {
    __shared__ int sd[512];
    __shared__ float sacc[512];
    const int t = threadIdx.x;
    float acc = 0.0f;

    for (int b = 0; b < BATCH; ++b) {
        int v = 0;
        if (t < NHIST) v = (int)ws[b * 512 + t] - (int)ws[HG_OFF + b * 512 + t];
        sd[t] = v;
        __syncthreads();
        // Hillis-Steele inclusive scan over 512 entries (entries >= 501 are 0)
        for (int off = 1; off < 512; off <<= 1) {
            int add = (t >= off) ? sd[t - off] : 0;
            __syncthreads();
            sd[t] += add;
            __syncthreads();
        }
        const int total = sd[NHIST - 1];          // == 0 mathematically, kept for safety
        const float denom = (float)ws[MC_OFF + b] + 1e-6f;
        if (t < NBINS) {
            // count_ge[j] diff = sum_{k>=j+1} d[k] = total - incl_prefix[j]
            float diff = (float)(total - sd[t]) / denom;
            acc += diff * diff;
        }
        __syncthreads();   // before sd reuse next batch
    }

    sacc[t] = acc;
    __syncthreads();
    for (int off = 256; off > 0; off >>= 1) {
        if (t < off) sacc[t] += sacc[t + off];
        __syncthreads();
    }
    if (t == 0) out[0] = sacc[0] * (1.0f / (BATCH * NBINS));
}

extern "C" void kernel_launch(void* const* d_in, const int* in_sizes, int n_in,
                              void* d_out, int out_size, void* d_ws, size_t ws_size,
                              hipStream_t stream) {
    const float4* dp = (const float4*)d_in[0];   // d_pred
    const float4* dg = (const float4*)d_in[1];   // d_gt
    const float4* dm = (const float4*)d_in[2];   // mask
    unsigned int* ws = (unsigned int*)d_ws;

    hipMemsetAsync(d_ws, 0, WS_UINTS * sizeof(unsigned int), stream);

    dim3 grid(BLOCKS_PER_BATCH, BATCH);
    dvh_hist_kernel<<<grid, dim3(THREADS), 0, stream>>>(dp, dg, dm, ws);
    dvh_reduce_kernel<<<1, dim3(512), 0, stream>>>(ws, (float*)d_out);
}

// Round 2
// 129.827 us; speedup vs baseline: 1.0714x; 1.0714x over previous
//
#include <hip/hip_runtime.h>
#include <stdint.h>

// DVH global loss, MI355X.
// B=4 batches, N=2^21 voxels/batch, 500 bins over [0,75].
// loss = mean_{b,j} ( suffix_sum_{k>j}(hist_p[b]-hist_g[b])[k] / (maskcount_b+1e-6) )^2

#define NBINS 500
#define NHIST 501          // searchsorted index c in [0,500]; c>=1 for d>=0
#define BATCH 4
#define NPB (1 << 21)      // elements per batch
#define VPB (NPB / 4)      // float4 per batch
#define THREADS 1024       // 16 waves/block, 2 blocks/CU -> 32 waves/CU (full occ)
#define BLOCKS_PER_BATCH 128

// workspace layout (uint32):
//   hist_pred : [b*512 + i], i<501, b<4      (offset 0)
//   hist_gt   : [2048 + b*512 + i]
//   maskcount : [4096 + b]
#define HG_OFF 2048
#define MC_OFF 4096
#define WS_UINTS 4100

__device__ __forceinline__ int bin_of(float d) {
    // c = # of fp32 bins k*STEP that are <= d  (jnp.linspace(0,75,500),
    // searchsorted side='right'); d >= 0 guaranteed.
    const float STEP = 75.0f / 499.0f;
    const float INV  = 499.0f / 75.0f;
    int k = (int)(d * INV);
    if (k > 499) k = 499;
    if ((float)k * STEP > d) --k;
    else if (k < 499 && (float)(k + 1) * STEP <= d) ++k;
    if ((float)k * STEP > d) --k;   // safety second pass (k>=0 since bins[0]=0<=d)
    return k + 1;                   // in [1,500]
}

__global__ __launch_bounds__(THREADS) void dvh_hist_kernel(
        const float4* __restrict__ dp, const float4* __restrict__ dg,
        const float4* __restrict__ dm, unsigned int* __restrict__ ws) {
    __shared__ unsigned int shp[NHIST];
    __shared__ unsigned int shg[NHIST];
    __shared__ unsigned int smc;
    const int b = blockIdx.y;
    for (int i = threadIdx.x; i < NHIST; i += THREADS) { shp[i] = 0u; shg[i] = 0u; }
    if (threadIdx.x == 0) smc = 0u;
    __syncthreads();

    const size_t base = (size_t)b * VPB;
    unsigned int myc = 0;
    for (int i = blockIdx.x * THREADS + threadIdx.x; i < VPB;
         i += BLOCKS_PER_BATCH * THREADS) {
        float4 p = dp[base + i];
        float4 g = dg[base + i];
        float4 m = dm[base + i];
        if (m.x != 0.0f) { atomicAdd(&shp[bin_of(p.x)], 1u); atomicAdd(&shg[bin_of(g.x)], 1u); ++myc; }
        if (m.y != 0.0f) { atomicAdd(&shp[bin_of(p.y)], 1u); atomicAdd(&shg[bin_of(g.y)], 1u); ++myc; }
        if (m.z != 0.0f) { atomicAdd(&shp[bin_of(p.z)], 1u); atomicAdd(&shg[bin_of(g.z)], 1u); ++myc; }
        if (m.w != 0.0f) { atomicAdd(&shp[bin_of(p.w)], 1u); atomicAdd(&shg[bin_of(g.w)], 1u); ++myc; }
    }
    if (myc) atomicAdd(&smc, myc);
    __syncthreads();

    for (int i = threadIdx.x; i < NHIST; i += THREADS) {
        unsigned int vp = shp[i]; if (vp) atomicAdd(&ws[b * 512 + i], vp);
        unsigned int vg = shg[i]; if (vg) atomicAdd(&ws[HG_OFF + b * 512 + i], vg);
    }
    if (threadIdx.x == 0 && smc) atomicAdd(&ws[MC_OFF + b], smc);
}

__global__ __launch_bounds__(512) void dvh_reduce_kernel(
        const unsigned int* __restrict__ ws, float* __restrict__ out) {
    __shared__ int wtot[8];
    __shared__ float facc[8];
    const int t = threadIdx.x;
    const int lane = t & 63;
    const int w = t >> 6;
    float acc = 0.0f;

    for (int b = 0; b < BATCH; ++b) {
        int v = 0;
        if (t < NHIST) v = (int)ws[b * 512 + t] - (int)ws[HG_OFF + b * 512 + t];
        // intra-wave inclusive scan (no barriers)
        #pragma unroll
        for (int off = 1; off < 64; off <<= 1) {
            int n = __shfl_up(v, off, 64);
            if (lane >= off) v += n;
        }
        if (lane == 63) wtot[w] = v;
        __syncthreads();
        int offset = 0, total = 0;
        #pragma unroll
        for (int i = 0; i < 8; ++i) {
            int x = wtot[i];
            total += x;
            if (i < w) offset += x;
        }
        const int prefix = v + offset;   // inclusive prefix over hist-diff[0..t]
        const float denom = (float)ws[MC_OFF + b] + 1e-6f;
        if (t < NBINS) {
            // count_ge[j] diff = sum_{k>=j+1} d[k] = total - incl_prefix[j]
            float diff = (float)(total - prefix) / denom;
            acc += diff * diff;
        }
        __syncthreads();   // before wtot reuse next batch
    }

    // block reduction of acc
    #pragma unroll
    for (int off = 32; off > 0; off >>= 1) acc += __shfl_down(acc, off, 64);
    if (lane == 0) facc[w] = acc;
    __syncthreads();
    if (t == 0) {
        float s = 0.0f;
        #pragma unroll
        for (int i = 0; i < 8; ++i) s += facc[i];
        out[0] = s * (1.0f / (BATCH * NBINS));
    }
}

extern "C" void kernel_launch(void* const* d_in, const int* in_sizes, int n_in,
                              void* d_out, int out_size, void* d_ws, size_t ws_size,
                              hipStream_t stream) {
    const float4* dp = (const float4*)d_in[0];   // d_pred
    const float4* dg = (const float4*)d_in[1];   // d_gt
    const float4* dm = (const float4*)d_in[2];   // mask
    unsigned int* ws = (unsigned int*)d_ws;

    hipMemsetAsync(d_ws, 0, WS_UINTS * sizeof(unsigned int), stream);

    dim3 grid(BLOCKS_PER_BATCH, BATCH);
    dvh_hist_kernel<<<grid, dim3(THREADS), 0, stream>>>(dp, dg, dm, ws);
    dvh_reduce_kernel<<<1, dim3(512), 0, stream>>>(ws, (float*)d_out);
}

// Round 3
// 126.057 us; speedup vs baseline: 1.1034x; 1.0299x over previous
//
#include <hip/hip_runtime.h>
#include <stdint.h>

// DVH global loss, MI355X.
// B=4 batches, N=2^21 voxels/batch, 500 bins over [0,75].
// loss = mean_{b,j} ( suffix_sum_{k>j}(hist_p[b]-hist_g[b])[k] / (maskcount_b+1e-6) )^2
// Only the DIFFERENCE histogram matters: d[i] = hist_p[i] - hist_g[i] (exact in ints).

#define NBINS 500
#define NHIST 501          // searchsorted index c in [0,500]; c>=1 for d>=0
#define BATCH 4
#define NPB (1 << 21)      // elements per batch
#define VPB (NPB / 4)      // float4 per batch
#define THREADS 1024
#define BLOCKS_PER_BATCH 128
#define STRIDE (BLOCKS_PER_BATCH * THREADS)   // 131072 float4s; VPB/STRIDE == 4

// workspace layout (int32):
//   hist_diff : [b*512 + i], i<501, b<4      (offset 0)
//   maskcount : [2048 + b]
#define MC_OFF 2048
#define WS_INTS 2052

__device__ __forceinline__ int bin_of(float d) {
    // c = # of fp32 bins k*STEP that are <= d  (jnp.linspace(0,75,500),
    // searchsorted side='right'); d >= 0 guaranteed.
    const float STEP = 75.0f / 499.0f;
    const float INV  = 499.0f / 75.0f;
    int k = (int)(d * INV);
    if (k > 499) k = 499;
    if ((float)k * STEP > d) --k;
    else if (k < 499 && (float)(k + 1) * STEP <= d) ++k;
    if ((float)k * STEP > d) --k;   // safety second pass (k>=0 since bins[0]=0<=d)
    return k + 1;                   // in [1,500]
}

__global__ __launch_bounds__(THREADS) void dvh_hist_kernel(
        const float4* __restrict__ dp, const float4* __restrict__ dg,
        const float4* __restrict__ dm, int* __restrict__ ws) {
    __shared__ int shd[NHIST];
    __shared__ unsigned int smc;
    const int b = blockIdx.y;
    for (int i = threadIdx.x; i < NHIST; i += THREADS) shd[i] = 0;
    if (threadIdx.x == 0) smc = 0u;
    __syncthreads();

    // Each thread owns exactly 4 float4s per array. Issue all 12 independent
    // loads before any use -> 12 outstanding vmem ops/thread (latency hiding
    // via ILP; R2 showed occupancy alone doesn't fix the 12-VGPR serial loop).
    const size_t base = (size_t)b * VPB + blockIdx.x * THREADS + threadIdx.x;
    float4 m0 = dm[base];              float4 m1 = dm[base + STRIDE];
    float4 m2 = dm[base + 2 * STRIDE]; float4 m3 = dm[base + 3 * STRIDE];
    float4 p0 = dp[base];              float4 p1 = dp[base + STRIDE];
    float4 p2 = dp[base + 2 * STRIDE]; float4 p3 = dp[base + 3 * STRIDE];
    float4 g0 = dg[base];              float4 g1 = dg[base + STRIDE];
    float4 g2 = dg[base + 2 * STRIDE]; float4 g3 = dg[base + 3 * STRIDE];

    unsigned int myc = 0;
#define DO(mm, pp, gg) \
    if (mm != 0.0f) { atomicAdd(&shd[bin_of(pp)], 1); atomicAdd(&shd[bin_of(gg)], -1); ++myc; }
    DO(m0.x, p0.x, g0.x) DO(m0.y, p0.y, g0.y) DO(m0.z, p0.z, g0.z) DO(m0.w, p0.w, g0.w)
    DO(m1.x, p1.x, g1.x) DO(m1.y, p1.y, g1.y) DO(m1.z, p1.z, g1.z) DO(m1.w, p1.w, g1.w)
    DO(m2.x, p2.x, g2.x) DO(m2.y, p2.y, g2.y) DO(m2.z, p2.z, g2.z) DO(m2.w, p2.w, g2.w)
    DO(m3.x, p3.x, g3.x) DO(m3.y, p3.y, g3.y) DO(m3.z, p3.z, g3.z) DO(m3.w, p3.w, g3.w)
#undef DO
    if (myc) atomicAdd(&smc, myc);
    __syncthreads();

    for (int i = threadIdx.x; i < NHIST; i += THREADS) {
        int v = shd[i];
        if (v) atomicAdd(&ws[b * 512 + i], v);
    }
    if (threadIdx.x == 0 && smc) atomicAdd((unsigned int*)&ws[MC_OFF + b], smc);
}

__global__ __launch_bounds__(512) void dvh_reduce_kernel(
        const int* __restrict__ ws, float* __restrict__ out) {
    __shared__ int wtot[8];
    __shared__ float facc[8];
    const int t = threadIdx.x;
    const int lane = t & 63;
    const int w = t >> 6;
    float acc = 0.0f;

    for (int b = 0; b < BATCH; ++b) {
        int v = (t < NHIST) ? ws[b * 512 + t] : 0;
        // intra-wave inclusive scan (no barriers)
        #pragma unroll
        for (int off = 1; off < 64; off <<= 1) {
            int n = __shfl_up(v, off, 64);
            if (lane >= off) v += n;
        }
        if (lane == 63) wtot[w] = v;
        __syncthreads();
        int offset = 0, total = 0;
        #pragma unroll
        for (int i = 0; i < 8; ++i) {
            int x = wtot[i];
            total += x;
            if (i < w) offset += x;
        }
        const int prefix = v + offset;   // inclusive prefix over hist-diff[0..t]
        const float denom = (float)((unsigned int)ws[MC_OFF + b]) + 1e-6f;
        if (t < NBINS) {
            // count_ge[j] diff = sum_{k>=j+1} d[k] = total - incl_prefix[j]
            float diff = (float)(total - prefix) / denom;
            acc += diff * diff;
        }
        __syncthreads();   // before wtot reuse next batch
    }

    // block reduction of acc
    #pragma unroll
    for (int off = 32; off > 0; off >>= 1) acc += __shfl_down(acc, off, 64);
    if (lane == 0) facc[w] = acc;
    __syncthreads();
    if (t == 0) {
        float s = 0.0f;
        #pragma unroll
        for (int i = 0; i < 8; ++i) s += facc[i];
        out[0] = s * (1.0f / (BATCH * NBINS));
    }
}

extern "C" void kernel_launch(void* const* d_in, const int* in_sizes, int n_in,
                              void* d_out, int out_size, void* d_ws, size_t ws_size,
                              hipStream_t stream) {
    const float4* dp = (const float4*)d_in[0];   // d_pred
    const float4* dg = (const float4*)d_in[1];   // d_gt
    const float4* dm = (const float4*)d_in[2];   // mask
    int* ws = (int*)d_ws;

    hipMemsetAsync(d_ws, 0, WS_INTS * sizeof(int), stream);

    dim3 grid(BLOCKS_PER_BATCH, BATCH);
    dvh_hist_kernel<<<grid, dim3(THREADS), 0, stream>>>(dp, dg, dm, ws);
    dvh_reduce_kernel<<<1, dim3(512), 0, stream>>>(ws, (float*)d_out);
}